// Round 1
// 265.313 us; speedup vs baseline: 1.0334x; 1.0334x over previous
//
#include <hip/hip_runtime.h>

typedef __bf16 bf16_t;
typedef __bf16 bf16x8 __attribute__((ext_vector_type(8)));
typedef __bf16 bf16x4 __attribute__((ext_vector_type(4)));
typedef float f32x4 __attribute__((ext_vector_type(4)));
typedef unsigned short ushort_t;

#define T_SEQ 2048
#define C_DIM 1024
#define NH    16
#define HD    64

__device__ __forceinline__ ushort_t f2bf(float f) {
    unsigned u = __builtin_bit_cast(unsigned, f);
    u += 0x7FFFu + ((u >> 16) & 1u);   // RNE
    return (ushort_t)(u >> 16);
}

// ---------------------------------------------------------------------------
// Unified fp32 -> bf16 conversion for x, Wq, Wk, Wv (single launch).
// ---------------------------------------------------------------------------
#define X4  2097152
#define W4  262144
__global__ __launch_bounds__(256)
void cvt_all_kernel(const float* __restrict__ x,  const float* __restrict__ Wq,
                    const float* __restrict__ Wk, const float* __restrict__ Wv,
                    ushort_t* __restrict__ xb,  ushort_t* __restrict__ Wqb,
                    ushort_t* __restrict__ Wkb, ushort_t* __restrict__ Wvb) {
    int i = blockIdx.x * 256 + threadIdx.x;
    const float* src; ushort_t* dst; int off;
    if (i < X4)                { src = x;  dst = xb;  off = i; }
    else if (i < X4 + W4)      { src = Wq; dst = Wqb; off = i - X4; }
    else if (i < X4 + 2 * W4)  { src = Wk; dst = Wkb; off = i - X4 - W4; }
    else                       { src = Wv; dst = Wvb; off = i - X4 - 2 * W4; }
    float4 f = ((const float4*)src)[off];
    ushort4 u;
    u.x = f2bf(f.x); u.y = f2bf(f.y); u.z = f2bf(f.z); u.w = f2bf(f.w);
    ((ushort4*)dst)[off] = u;
}

// ---------------------------------------------------------------------------
// GEMM core: 128x128 tile, BK=64, 256 threads (4 waves, 2x2), NT layout.
// ---------------------------------------------------------------------------
template<bool AF32, bool BF32>
__device__ __forceinline__ void gemm_core_128(const void* __restrict__ Araw,
                                              const void* __restrict__ Braw,
                                              f32x4 (&acc)[4][4]) {
    __shared__ alignas(16) ushort_t As[128 * 72];
    __shared__ alignas(16) ushort_t Ws[128 * 72];
    const int tid  = threadIdx.x;
    const int lane = tid & 63;
    const int wv   = tid >> 6;
    const int wm   = wv >> 1, wn = wv & 1;
    const int quad = lane >> 4, ln = lane & 15;
    const int m0 = blockIdx.x * 128, n0 = blockIdx.y * 128;

    f32x4 z4 = {0.f, 0.f, 0.f, 0.f};
#pragma unroll
    for (int i = 0; i < 4; i++)
#pragma unroll
        for (int j = 0; j < 4; j++) acc[i][j] = z4;

    for (int kt = 0; kt < 1024; kt += 64) {
        if (AF32) {
            const float* A = (const float*)Araw;
#pragma unroll
            for (int p = 0; p < 8; ++p) {
                int cid = p * 256 + tid;
                int row = cid >> 4, c4 = (cid & 15) * 4;
                float4 f = *(const float4*)(A + (size_t)(m0 + row) * 1024 + kt + c4);
                ushort4 u;
                u.x = f2bf(f.x); u.y = f2bf(f.y); u.z = f2bf(f.z); u.w = f2bf(f.w);
                *(ushort4*)&As[row * 72 + c4] = u;
            }
        } else {
            const bf16_t* A = (const bf16_t*)Araw;
#pragma unroll
            for (int p = 0; p < 4; ++p) {
                int cid = p * 256 + tid;
                int row = cid >> 3, c8 = (cid & 7) * 8;
                *(uint4*)&As[row * 72 + c8] =
                    *(const uint4*)(A + (size_t)(m0 + row) * 1024 + kt + c8);
            }
        }
        if (BF32) {
            const float* Bm = (const float*)Braw;
#pragma unroll
            for (int p = 0; p < 8; ++p) {
                int cid = p * 256 + tid;
                int row = cid >> 4, c4 = (cid & 15) * 4;
                float4 f = *(const float4*)(Bm + (size_t)(n0 + row) * 1024 + kt + c4);
                ushort4 u;
                u.x = f2bf(f.x); u.y = f2bf(f.y); u.z = f2bf(f.z); u.w = f2bf(f.w);
                *(ushort4*)&Ws[row * 72 + c4] = u;
            }
        } else {
            const bf16_t* Bm = (const bf16_t*)Braw;
#pragma unroll
            for (int p = 0; p < 4; ++p) {
                int cid = p * 256 + tid;
                int row = cid >> 3, c8 = (cid & 7) * 8;
                *(uint4*)&Ws[row * 72 + c8] =
                    *(const uint4*)(Bm + (size_t)(n0 + row) * 1024 + kt + c8);
            }
        }
        __syncthreads();
#pragma unroll
        for (int ks = 0; ks < 2; ++ks) {
            bf16x8 af[4], bfr[4];
#pragma unroll
            for (int i = 0; i < 4; i++)
                af[i] = *(const bf16x8*)&As[(wm * 64 + i * 16 + ln) * 72 + ks * 32 + quad * 8];
#pragma unroll
            for (int j = 0; j < 4; j++)
                bfr[j] = *(const bf16x8*)&Ws[(wn * 64 + j * 16 + ln) * 72 + ks * 32 + quad * 8];
#pragma unroll
            for (int i = 0; i < 4; i++)
#pragma unroll
                for (int j = 0; j < 4; j++)
                    acc[i][j] = __builtin_amdgcn_mfma_f32_16x16x32_bf16(af[i], bfr[j],
                                                                        acc[i][j], 0, 0, 0);
        }
        __syncthreads();
    }
}

// ---------------------------------------------------------------------------
// QKV projection (all-bf16 inputs).  z=0: Q (pre-scaled by cscale) -> [B,H,T,D];
// z=1: K -> [B,H,T,D]; z=2: V -> [B,H,D,T].  Biases fp32.
// ---------------------------------------------------------------------------
__global__ __launch_bounds__(256, 2)
void qkv_gemm_kernel(const bf16_t* __restrict__ xb,
                     const bf16_t* __restrict__ Wqb, const float* __restrict__ bq,
                     const bf16_t* __restrict__ Wkb, const float* __restrict__ bk,
                     const bf16_t* __restrict__ Wvb, const float* __restrict__ bv,
                     ushort_t* __restrict__ Qo, ushort_t* __restrict__ Ko,
                     ushort_t* __restrict__ Vo) {
    const int z = blockIdx.z;
    const bf16_t* W   = (z == 0) ? Wqb : (z == 1) ? Wkb : Wvb;
    const float* bias = (z == 0) ? bq : (z == 1) ? bk : bv;
    ushort_t* outp    = (z == 0) ? Qo : (z == 1) ? Ko : Vo;
    const float fs    = (z == 0) ? 0.18033688011112042f : 1.0f;  // (1/8)*log2(e)

    f32x4 acc[4][4];
    gemm_core_128<false, false>(xb, W, acc);

    const int tid  = threadIdx.x;
    const int lane = tid & 63;
    const int wv2  = tid >> 6;
    const int wm   = wv2 >> 1, wn = wv2 & 1;
    const int quad = lane >> 4, ln = lane & 15;
    const int mbase = blockIdx.x * 128 + wm * 64;
    const int nbase = blockIdx.y * 128 + wn * 64;

#pragma unroll
    for (int j = 0; j < 4; j++) {
        int n = nbase + j * 16 + ln;
        float bj = bias[n];
        int h = n >> 6, d = n & 63;
#pragma unroll
        for (int i = 0; i < 4; i++) {
            int mr = mbase + i * 16 + quad * 4;
            int b = mr >> 11;
            int t = mr & 2047;
            if (z < 2) {
                ushort_t* op = outp + ((size_t)(b * NH + h) * T_SEQ + t) * HD + d;
#pragma unroll
                for (int r = 0; r < 4; r++)
                    op[(size_t)r * HD] = f2bf((acc[i][j][r] + bj) * fs);
            } else {
                ushort4 us;
                us.x = f2bf(acc[i][j][0] + bj);
                us.y = f2bf(acc[i][j][1] + bj);
                us.z = f2bf(acc[i][j][2] + bj);
                us.w = f2bf(acc[i][j][3] + bj);
                *(ushort4*)(outp + ((size_t)(b * NH + h) * HD + d) * T_SEQ + t) = us;
            }
        }
    }
}

// ---------------------------------------------------------------------------
// QK^T with SWAPPED operands: zz = mfma(K_frag, Q_frag) -> lane (quad,ln)
// holds S[q=wv*16+ln][s = n16*16 + quad*4 + r], i.e. 4 CONSECUTIVE s-columns
// of a single q-row.  exp2 + pack -> one ds_write_b64 per n16 into row-major
// P[q][s] (stride 72) — exactly the layout the PV A-fragment reads back.
// Kills the 16 scalar ds_write_b16 + their bank conflicts per phase.
// ---------------------------------------------------------------------------
__device__ __forceinline__ void qk_softmax(const ushort_t* __restrict__ Ks,
                                           bf16_t* __restrict__ PsW,
                                           bf16x8 aq0, bf16x8 aq1,
                                           bool diag, int wv, int quad, int ln) {
#pragma unroll
    for (int n16 = 0; n16 < 4; n16++) {
        f32x4 zz = {0.f, 0.f, 0.f, 0.f};
        bf16x8 bk0 = *(const bf16x8*)&Ks[(n16 * 16 + ln) * 72 + quad * 8];
        zz = __builtin_amdgcn_mfma_f32_16x16x32_bf16(bk0, aq0, zz, 0, 0, 0);
        bf16x8 bk1 = *(const bf16x8*)&Ks[(n16 * 16 + ln) * 72 + 32 + quad * 8];
        zz = __builtin_amdgcn_mfma_f32_16x16x32_bf16(bk1, aq1, zz, 0, 0, 0);
        bf16x4 pb;
#pragma unroll
        for (int r = 0; r < 4; r++) {
            float v = zz[r];
            // s = n16*16+quad*4+r ; q = wv*16+ln ; mask s > q on diag tile
            v = (diag && (n16 * 16 + quad * 4 + r > wv * 16 + ln)) ? -1e30f : v;
            pb[r] = (bf16_t)__builtin_amdgcn_exp2f(v);
        }
        *(bf16x4*)&PsW[ln * 72 + n16 * 16 + quad * 4] = pb;
    }
}

// ---------------------------------------------------------------------------
// Flash attention (causal), paired q-tiles (block p: q-tiles p and 31-p of
// one (b,h)); shared staged K/V tiles; register prefetch; per-phase Ps
// buffers; merged PV so V fragments are read from LDS once for both phases.
// XCD-aware block remap: all 16 q-blocks of one (b,h) share L%8 -> one XCD,
// keeping that head's K/V (512 KB) L2-resident.
// ---------------------------------------------------------------------------
__global__ __launch_bounds__(256, 4)
void flash_kernel(const ushort_t* __restrict__ Qw, const ushort_t* __restrict__ Kw,
                  const ushort_t* __restrict__ Vt, ushort_t* __restrict__ Y) {
    __shared__ alignas(16) ushort_t Ks[64 * 72];
    __shared__ alignas(16) ushort_t Vts[64 * 72];
    __shared__ alignas(16) bf16_t PsA[4 * 16 * 72];
    __shared__ alignas(16) bf16_t PsB[4 * 16 * 72];

    const int tid  = threadIdx.x;
    const int lane = tid & 63;
    const int wv   = tid >> 6;
    const int quad = lane >> 4, ln = lane & 15;
    // bijective XCD-aware remap of (p, bh)
    const int L  = blockIdx.y * 16 + blockIdx.x;      // hw dispatch-linear id
    const int m  = L >> 3;
    const int bh = ((m >> 4) << 3) | (L & 7);         // same bh -> same L%8 (XCD)
    const int p  = m & 15;                            // 0..15
    const int qa = p, qb = 31 - p;
    const int b = bh >> 4, h = bh & 15;
    bf16_t* PsWA = &PsA[wv * 1152];
    bf16_t* PsWB = &PsB[wv * 1152];

    bf16x8 ones;
#pragma unroll
    for (int i = 0; i < 8; i++) ones[i] = (bf16_t)1.0f;

    const ushort_t* qpa = Qw + ((size_t)bh * T_SEQ + qa * 64 + wv * 16 + ln) * HD;
    const ushort_t* qpb = Qw + ((size_t)bh * T_SEQ + qb * 64 + wv * 16 + ln) * HD;
    bf16x8 aqA0 = *(const bf16x8*)(qpa + quad * 8);
    bf16x8 aqA1 = *(const bf16x8*)(qpa + 32 + quad * 8);
    bf16x8 aqB0 = *(const bf16x8*)(qpb + quad * 8);
    bf16x8 aqB1 = *(const bf16x8*)(qpb + 32 + quad * 8);

    f32x4 oA[4], oB[4];
    f32x4 z4 = {0.f, 0.f, 0.f, 0.f};
#pragma unroll
    for (int i = 0; i < 4; i++) { oA[i] = z4; oB[i] = z4; }
    f32x4 lA4 = z4, lB4 = z4;

    const int row0 = tid >> 3, c80 = (tid & 7) * 8;
    const int row1 = (256 + tid) >> 3, c81 = c80;

    uint4 pk0, pk1, pv0, pv1;
    pk0 = *(const uint4*)(Kw + ((size_t)bh * T_SEQ + row0) * HD + c80);
    pv0 = *(const uint4*)(Vt + ((size_t)bh * HD + row0) * T_SEQ + c80);
    pk1 = *(const uint4*)(Kw + ((size_t)bh * T_SEQ + row1) * HD + c81);
    pv1 = *(const uint4*)(Vt + ((size_t)bh * HD + row1) * T_SEQ + c81);

    for (int st = 0; st <= qb; ++st) {
        __syncthreads();
        *(uint4*)&Ks[row0 * 72 + c80]  = pk0;
        *(uint4*)&Vts[row0 * 72 + c80] = pv0;
        *(uint4*)&Ks[row1 * 72 + c81]  = pk1;
        *(uint4*)&Vts[row1 * 72 + c81] = pv1;
        if (st < qb) {
            int s1 = (st + 1) * 64;
            pk0 = *(const uint4*)(Kw + ((size_t)bh * T_SEQ + s1 + row0) * HD + c80);
            pv0 = *(const uint4*)(Vt + ((size_t)bh * HD + row0) * T_SEQ + s1 + c80);
            pk1 = *(const uint4*)(Kw + ((size_t)bh * T_SEQ + s1 + row1) * HD + c81);
            pv1 = *(const uint4*)(Vt + ((size_t)bh * HD + row1) * T_SEQ + s1 + c81);
        }
        __syncthreads();

        const bool doA = (st <= qa);
        if (doA)
            qk_softmax(Ks, PsWA, aqA0, aqA1, st == qa, wv, quad, ln);
        qk_softmax(Ks, PsWB, aqB0, aqB1, st == qb, wv, quad, ln);

        // merged PV: each V fragment read once, feeds both phases' MFMAs
#pragma unroll
        for (int ks = 0; ks < 2; ks++) {
            bf16x8 apA, apB;
            if (doA) {
                apA = *(const bf16x8*)&PsWA[ln * 72 + ks * 32 + quad * 8];
                lA4 = __builtin_amdgcn_mfma_f32_16x16x32_bf16(apA, ones, lA4, 0, 0, 0);
            }
            apB = *(const bf16x8*)&PsWB[ln * 72 + ks * 32 + quad * 8];
            lB4 = __builtin_amdgcn_mfma_f32_16x16x32_bf16(apB, ones, lB4, 0, 0, 0);
#pragma unroll
            for (int d16 = 0; d16 < 4; d16++) {
                bf16x8 bv = *(const bf16x8*)&Vts[(d16 * 16 + ln) * 72 + ks * 32 + quad * 8];
                if (doA)
                    oA[d16] = __builtin_amdgcn_mfma_f32_16x16x32_bf16(apA, bv, oA[d16], 0, 0, 0);
                oB[d16] = __builtin_amdgcn_mfma_f32_16x16x32_bf16(apB, bv, oB[d16], 0, 0, 0);
            }
        }
    }

    // epilogue: normalize (l4 reg r = rowsum of row quad*4+r) and store
#pragma unroll
    for (int ph = 0; ph < 2; ph++) {
        f32x4* o = ph ? oB : oA;
        f32x4 l4 = ph ? lB4 : lA4;
        int qt = ph ? qb : qa;
        f32x4 inv = {1.f / l4[0], 1.f / l4[1], 1.f / l4[2], 1.f / l4[3]};
        const int tg = qt * 64 + wv * 16 + quad * 4;
#pragma unroll
        for (int d16 = 0; d16 < 4; d16++) {
#pragma unroll
            for (int r = 0; r < 4; r++) {
                float v = o[d16][r] * inv[r];
                Y[((size_t)b * T_SEQ + tg + r) * C_DIM + h * HD + d16 * 16 + ln] = f2bf(v);
            }
        }
    }
}

// ---------------------------------------------------------------------------
// Output projection: out[m,n] = sum_k Y[m,k] * Wp[n,k] + bp[n]  (fp32 out)
// ---------------------------------------------------------------------------
__global__ __launch_bounds__(256, 2)
void proj_gemm_kernel(const bf16_t* __restrict__ Yw, const float* __restrict__ Wp,
                      const float* __restrict__ bp, float* __restrict__ out) {
    f32x4 acc[4][4];
    gemm_core_128<false, true>(Yw, Wp, acc);

    const int tid  = threadIdx.x;
    const int lane = tid & 63;
    const int wv2  = tid >> 6;
    const int wm   = wv2 >> 1, wn = wv2 & 1;
    const int quad = lane >> 4, ln = lane & 15;
    const int mbase = blockIdx.x * 128 + wm * 64;
    const int nbase = blockIdx.y * 128 + wn * 64;

#pragma unroll
    for (int j = 0; j < 4; j++) {
        int n = nbase + j * 16 + ln;
        float bj = bp[n];
#pragma unroll
        for (int i = 0; i < 4; i++) {
            int mr = mbase + i * 16 + quad * 4;
#pragma unroll
            for (int r = 0; r < 4; r++)
                out[(size_t)(mr + r) * C_DIM + n] = acc[i][j][r] + bj;
        }
    }
}

// ---------------------------------------------------------------------------
extern "C" void kernel_launch(void* const* d_in, const int* in_sizes, int n_in,
                              void* d_out, int out_size, void* d_ws, size_t ws_size,
                              hipStream_t stream) {
    const float* x  = (const float*)d_in[0];
    const float* Wq = (const float*)d_in[1];
    const float* bq = (const float*)d_in[2];
    const float* Wk = (const float*)d_in[3];
    const float* bk = (const float*)d_in[4];
    const float* Wv = (const float*)d_in[5];
    const float* bv = (const float*)d_in[6];
    const float* Wp = (const float*)d_in[7];
    const float* bp = (const float*)d_in[8];
    float* out = (float*)d_out;

    char* ws = (char*)d_ws;
    const size_t MB = (size_t)1 << 20;
    ushort_t* Qw = (ushort_t*)(ws);            // 16 MB  [B,H,T,D] bf16 (pre-scaled)
    ushort_t* Kw = (ushort_t*)(ws + 16 * MB);  // 16 MB  [B,H,T,D] bf16
    ushort_t* Vt = (ushort_t*)(ws + 32 * MB);  // 16 MB  [B,H,D,T] bf16
    ushort_t* Yw = (ushort_t*)(ws + 48 * MB);  // 16 MB  [B,T,C]   bf16

    // d_out doubles as bf16 scratch for converted inputs; proj overwrites it.
    ushort_t* xb  = (ushort_t*)out;                     // 16 MB
    ushort_t* Wqb = (ushort_t*)((char*)out + 16 * MB);  // 2 MB
    ushort_t* Wkb = (ushort_t*)((char*)out + 18 * MB);  // 2 MB
    ushort_t* Wvb = (ushort_t*)((char*)out + 20 * MB);  // 2 MB

    cvt_all_kernel<<<11264, 256, 0, stream>>>(x, Wq, Wk, Wv, xb, Wqb, Wkb, Wvb);

    dim3 g1(64, 8, 3);
    qkv_gemm_kernel<<<g1, 256, 0, stream>>>((const bf16_t*)xb,
                                            (const bf16_t*)Wqb, bq,
                                            (const bf16_t*)Wkb, bk,
                                            (const bf16_t*)Wvb, bv,
                                            Qw, Kw, Vt);

    dim3 g2(16, 64);   // (paired q-tiles, B*H)
    flash_kernel<<<g2, 256, 0, stream>>>(Qw, Kw, Vt, Yw);

    dim3 g3(64, 8, 1);
    proj_gemm_kernel<<<g3, 256, 0, stream>>>((const bf16_t*)Yw, Wp, bp, out);
}

// Round 2
// 248.385 us; speedup vs baseline: 1.1039x; 1.0682x over previous
//
#include <hip/hip_runtime.h>

typedef __bf16 bf16_t;
typedef __bf16 bf16x8 __attribute__((ext_vector_type(8)));
typedef __bf16 bf16x4 __attribute__((ext_vector_type(4)));
typedef float f32x4 __attribute__((ext_vector_type(4)));
typedef unsigned short ushort_t;

#define T_SEQ 2048
#define C_DIM 1024
#define NH    16
#define HD    64

__device__ __forceinline__ ushort_t f2bf(float f) {
    unsigned u = __builtin_bit_cast(unsigned, f);
    u += 0x7FFFu + ((u >> 16) & 1u);   // RNE
    return (ushort_t)(u >> 16);
}

// async 16B global -> LDS (direct, no VGPR round-trip)
__device__ __forceinline__ void async_cp16(const void* g, void* l) {
    __builtin_amdgcn_global_load_lds(
        (const __attribute__((address_space(1))) void*)g,
        (__attribute__((address_space(3))) void*)l, 16, 0, 0);
}

// ---------------------------------------------------------------------------
// Unified fp32 -> bf16 conversion for x, Wq, Wk, Wv (single launch).
// ---------------------------------------------------------------------------
#define X4  2097152
#define W4  262144
__global__ __launch_bounds__(256)
void cvt_all_kernel(const float* __restrict__ x,  const float* __restrict__ Wq,
                    const float* __restrict__ Wk, const float* __restrict__ Wv,
                    ushort_t* __restrict__ xb,  ushort_t* __restrict__ Wqb,
                    ushort_t* __restrict__ Wkb, ushort_t* __restrict__ Wvb) {
    int i = blockIdx.x * 256 + threadIdx.x;
    const float* src; ushort_t* dst; int off;
    if (i < X4)                { src = x;  dst = xb;  off = i; }
    else if (i < X4 + W4)      { src = Wq; dst = Wqb; off = i - X4; }
    else if (i < X4 + 2 * W4)  { src = Wk; dst = Wkb; off = i - X4 - W4; }
    else                       { src = Wv; dst = Wvb; off = i - X4 - 2 * W4; }
    float4 f = ((const float4*)src)[off];
    ushort4 u;
    u.x = f2bf(f.x); u.y = f2bf(f.y); u.z = f2bf(f.z); u.w = f2bf(f.w);
    ((ushort4*)dst)[off] = u;
}

// fp32 -> bf16 for Wp (runs after flash; Wpb lives in the dead Qw region)
__global__ __launch_bounds__(256)
void cvt_wp_kernel(const float* __restrict__ Wp, ushort_t* __restrict__ Wpb) {
    int i = blockIdx.x * 256 + threadIdx.x;   // 262144 float4
    float4 f = ((const float4*)Wp)[i];
    ushort4 u;
    u.x = f2bf(f.x); u.y = f2bf(f.y); u.z = f2bf(f.z); u.w = f2bf(f.w);
    ((ushort4*)Wpb)[i] = u;
}

// ---------------------------------------------------------------------------
// GEMM core: 128x128 tile, BK=64, 256 threads (4 waves, 2x2), NT layout,
// all-bf16.  Staging via global_load_lds (16B/lane, linear LDS dest).
// XOR swizzle: phys 16B-block cp at row r holds logical block cp^(r&7);
// achieved by pre-swizzling the per-lane GLOBAL source (lane l fetches
// logical block (l&7)^(l>>3) of its row).  Fragment reads apply the same
// involution -> 2 lanes per 4-bank group = conflict-free ds_read_b128.
// ---------------------------------------------------------------------------
__device__ __forceinline__ void gemm_core_128(const bf16_t* __restrict__ A,
                                              const bf16_t* __restrict__ B,
                                              f32x4 (&acc)[4][4]) {
    __shared__ alignas(16) ushort_t As[128 * 64];
    __shared__ alignas(16) ushort_t Ws[128 * 64];
    const int tid  = threadIdx.x;
    const int lane = tid & 63;
    const int wv   = tid >> 6;
    const int wm   = wv >> 1, wn = wv & 1;
    const int quad = lane >> 4, ln = lane & 15;
    const int m0 = blockIdx.x * 128, n0 = blockIdx.y * 128;

    f32x4 z4 = {0.f, 0.f, 0.f, 0.f};
#pragma unroll
    for (int i = 0; i < 4; i++)
#pragma unroll
        for (int j = 0; j < 4; j++) acc[i][j] = z4;

    const int lr = lane >> 3;            // row within 8-row chunk
    const int lc = (lane & 7) ^ lr;      // swizzled source 16B-block
    // wave w chunk p covers rows (w*4+p)*8 .. +7
    const bf16_t* Ab = A + (size_t)(m0 + wv * 32 + lr) * 1024 + lc * 8;
    const bf16_t* Bb = B + (size_t)(n0 + wv * 32 + lr) * 1024 + lc * 8;

    for (int kt = 0; kt < 1024; kt += 64) {
#pragma unroll
        for (int p = 0; p < 4; ++p) {
            async_cp16(Ab + (size_t)p * 8192 + kt, &As[(wv * 4 + p) * 512]);
            async_cp16(Bb + (size_t)p * 8192 + kt, &Ws[(wv * 4 + p) * 512]);
        }
        __syncthreads();
#pragma unroll
        for (int ks = 0; ks < 2; ++ks) {
            bf16x8 af[4], bfr[4];
#pragma unroll
            for (int i = 0; i < 4; i++)
                af[i] = *(const bf16x8*)&As[(wm * 64 + i * 16 + ln) * 64 +
                                            (((ks * 4 + quad) ^ (ln & 7)) * 8)];
#pragma unroll
            for (int j = 0; j < 4; j++)
                bfr[j] = *(const bf16x8*)&Ws[(wn * 64 + j * 16 + ln) * 64 +
                                             (((ks * 4 + quad) ^ (ln & 7)) * 8)];
#pragma unroll
            for (int i = 0; i < 4; i++)
#pragma unroll
                for (int j = 0; j < 4; j++)
                    acc[i][j] = __builtin_amdgcn_mfma_f32_16x16x32_bf16(af[i], bfr[j],
                                                                        acc[i][j], 0, 0, 0);
        }
        __syncthreads();
    }
}

// ---------------------------------------------------------------------------
// QKV projection (all-bf16 inputs).  z=0: Q (pre-scaled by cscale) -> [B,H,T,D];
// z=1: K -> [B,H,T,D]; z=2: V -> [B,H,D,T].  Biases fp32.
// ---------------------------------------------------------------------------
__global__ __launch_bounds__(256, 3)
void qkv_gemm_kernel(const bf16_t* __restrict__ xb,
                     const bf16_t* __restrict__ Wqb, const float* __restrict__ bq,
                     const bf16_t* __restrict__ Wkb, const float* __restrict__ bk,
                     const bf16_t* __restrict__ Wvb, const float* __restrict__ bv,
                     ushort_t* __restrict__ Qo, ushort_t* __restrict__ Ko,
                     ushort_t* __restrict__ Vo) {
    const int z = blockIdx.z;
    const bf16_t* W   = (z == 0) ? Wqb : (z == 1) ? Wkb : Wvb;
    const float* bias = (z == 0) ? bq : (z == 1) ? bk : bv;
    ushort_t* outp    = (z == 0) ? Qo : (z == 1) ? Ko : Vo;
    const float fs    = (z == 0) ? 0.18033688011112042f : 1.0f;  // (1/8)*log2(e)

    f32x4 acc[4][4];
    gemm_core_128(xb, W, acc);

    const int tid  = threadIdx.x;
    const int lane = tid & 63;
    const int wv2  = tid >> 6;
    const int wm   = wv2 >> 1, wn = wv2 & 1;
    const int quad = lane >> 4, ln = lane & 15;
    const int mbase = blockIdx.x * 128 + wm * 64;
    const int nbase = blockIdx.y * 128 + wn * 64;

#pragma unroll
    for (int j = 0; j < 4; j++) {
        int n = nbase + j * 16 + ln;
        float bj = bias[n];
        int h = n >> 6, d = n & 63;
#pragma unroll
        for (int i = 0; i < 4; i++) {
            int mr = mbase + i * 16 + quad * 4;
            int b = mr >> 11;
            int t = mr & 2047;
            if (z < 2) {
                ushort_t* op = outp + ((size_t)(b * NH + h) * T_SEQ + t) * HD + d;
#pragma unroll
                for (int r = 0; r < 4; r++)
                    op[(size_t)r * HD] = f2bf((acc[i][j][r] + bj) * fs);
            } else {
                ushort4 us;
                us.x = f2bf(acc[i][j][0] + bj);
                us.y = f2bf(acc[i][j][1] + bj);
                us.z = f2bf(acc[i][j][2] + bj);
                us.w = f2bf(acc[i][j][3] + bj);
                *(ushort4*)(outp + ((size_t)(b * NH + h) * HD + d) * T_SEQ + t) = us;
            }
        }
    }
}

// ---------------------------------------------------------------------------
// Merged QK^T for BOTH q-phases with shared K-fragment loads (swapped
// operands: zz = mfma(K_frag, Q_frag) -> lane holds S[q=ln][s=n16*16+quad*4+r],
// 4 consecutive s of one q-row -> one packed ds_write_b64 per n16).
// ---------------------------------------------------------------------------
__device__ __forceinline__ void qk2_softmax(const ushort_t* __restrict__ Ks,
                                            bf16_t* __restrict__ PsWA,
                                            bf16_t* __restrict__ PsWB,
                                            bf16x8 aqA0, bf16x8 aqA1,
                                            bf16x8 aqB0, bf16x8 aqB1,
                                            bool doA, bool diagA, bool diagB,
                                            int wv, int quad, int ln) {
#pragma unroll
    for (int n16 = 0; n16 < 4; n16++) {
        bf16x8 bk0 = *(const bf16x8*)&Ks[(n16 * 16 + ln) * 72 + quad * 8];
        bf16x8 bk1 = *(const bf16x8*)&Ks[(n16 * 16 + ln) * 72 + 32 + quad * 8];
        f32x4 zB = {0.f, 0.f, 0.f, 0.f};
        zB = __builtin_amdgcn_mfma_f32_16x16x32_bf16(bk0, aqB0, zB, 0, 0, 0);
        zB = __builtin_amdgcn_mfma_f32_16x16x32_bf16(bk1, aqB1, zB, 0, 0, 0);
        if (doA) {
            f32x4 zA = {0.f, 0.f, 0.f, 0.f};
            zA = __builtin_amdgcn_mfma_f32_16x16x32_bf16(bk0, aqA0, zA, 0, 0, 0);
            zA = __builtin_amdgcn_mfma_f32_16x16x32_bf16(bk1, aqA1, zA, 0, 0, 0);
            bf16x4 pa;
#pragma unroll
            for (int r = 0; r < 4; r++) {
                float v = zA[r];
                v = (diagA && (n16 * 16 + quad * 4 + r > wv * 16 + ln)) ? -1e30f : v;
                pa[r] = (bf16_t)__builtin_amdgcn_exp2f(v);
            }
            *(bf16x4*)&PsWA[ln * 72 + n16 * 16 + quad * 4] = pa;
        }
        bf16x4 pb;
#pragma unroll
        for (int r = 0; r < 4; r++) {
            float v = zB[r];
            v = (diagB && (n16 * 16 + quad * 4 + r > wv * 16 + ln)) ? -1e30f : v;
            pb[r] = (bf16_t)__builtin_amdgcn_exp2f(v);
        }
        *(bf16x4*)&PsWB[ln * 72 + n16 * 16 + quad * 4] = pb;
    }
}

// ---------------------------------------------------------------------------
// Flash attention (causal), paired q-tiles (block p: q-tiles p and 31-p of
// one (b,h)); shared staged K/V tiles; register prefetch; shared K-fragment
// loads across phases; merged PV (V fragments read once for both phases).
// XCD-aware block remap keeps each (b,h)'s K/V L2-resident on one XCD.
// ---------------------------------------------------------------------------
__global__ __launch_bounds__(256, 4)
void flash_kernel(const ushort_t* __restrict__ Qw, const ushort_t* __restrict__ Kw,
                  const ushort_t* __restrict__ Vt, ushort_t* __restrict__ Y) {
    __shared__ alignas(16) ushort_t Ks[64 * 72];
    __shared__ alignas(16) ushort_t Vts[64 * 72];
    __shared__ alignas(16) bf16_t PsA[4 * 16 * 72];
    __shared__ alignas(16) bf16_t PsB[4 * 16 * 72];

    const int tid  = threadIdx.x;
    const int lane = tid & 63;
    const int wv   = tid >> 6;
    const int quad = lane >> 4, ln = lane & 15;
    // bijective XCD-aware remap of (p, bh)
    const int L  = blockIdx.y * 16 + blockIdx.x;      // hw dispatch-linear id
    const int m  = L >> 3;
    const int bh = ((m >> 4) << 3) | (L & 7);         // same bh -> same L%8 (XCD)
    const int p  = m & 15;                            // 0..15
    const int qa = p, qb = 31 - p;
    const int b = bh >> 4, h = bh & 15;
    bf16_t* PsWA = &PsA[wv * 1152];
    bf16_t* PsWB = &PsB[wv * 1152];

    bf16x8 ones;
#pragma unroll
    for (int i = 0; i < 8; i++) ones[i] = (bf16_t)1.0f;

    const ushort_t* qpa = Qw + ((size_t)bh * T_SEQ + qa * 64 + wv * 16 + ln) * HD;
    const ushort_t* qpb = Qw + ((size_t)bh * T_SEQ + qb * 64 + wv * 16 + ln) * HD;
    bf16x8 aqA0 = *(const bf16x8*)(qpa + quad * 8);
    bf16x8 aqA1 = *(const bf16x8*)(qpa + 32 + quad * 8);
    bf16x8 aqB0 = *(const bf16x8*)(qpb + quad * 8);
    bf16x8 aqB1 = *(const bf16x8*)(qpb + 32 + quad * 8);

    f32x4 oA[4], oB[4];
    f32x4 z4 = {0.f, 0.f, 0.f, 0.f};
#pragma unroll
    for (int i = 0; i < 4; i++) { oA[i] = z4; oB[i] = z4; }
    f32x4 lA4 = z4, lB4 = z4;

    const int row0 = tid >> 3, c80 = (tid & 7) * 8;
    const int row1 = (256 + tid) >> 3, c81 = c80;

    uint4 pk0, pk1, pv0, pv1;
    pk0 = *(const uint4*)(Kw + ((size_t)bh * T_SEQ + row0) * HD + c80);
    pv0 = *(const uint4*)(Vt + ((size_t)bh * HD + row0) * T_SEQ + c80);
    pk1 = *(const uint4*)(Kw + ((size_t)bh * T_SEQ + row1) * HD + c81);
    pv1 = *(const uint4*)(Vt + ((size_t)bh * HD + row1) * T_SEQ + c81);

    for (int st = 0; st <= qb; ++st) {
        __syncthreads();
        *(uint4*)&Ks[row0 * 72 + c80]  = pk0;
        *(uint4*)&Vts[row0 * 72 + c80] = pv0;
        *(uint4*)&Ks[row1 * 72 + c81]  = pk1;
        *(uint4*)&Vts[row1 * 72 + c81] = pv1;
        if (st < qb) {
            int s1 = (st + 1) * 64;
            pk0 = *(const uint4*)(Kw + ((size_t)bh * T_SEQ + s1 + row0) * HD + c80);
            pv0 = *(const uint4*)(Vt + ((size_t)bh * HD + row0) * T_SEQ + s1 + c80);
            pk1 = *(const uint4*)(Kw + ((size_t)bh * T_SEQ + s1 + row1) * HD + c81);
            pv1 = *(const uint4*)(Vt + ((size_t)bh * HD + row1) * T_SEQ + s1 + c81);
        }
        __syncthreads();

        const bool doA = (st <= qa);
        qk2_softmax(Ks, PsWA, PsWB, aqA0, aqA1, aqB0, aqB1,
                    doA, st == qa, st == qb, wv, quad, ln);

        // merged PV: each V fragment read once, feeds both phases' MFMAs
#pragma unroll
        for (int ks = 0; ks < 2; ks++) {
            bf16x8 apA, apB;
            if (doA) {
                apA = *(const bf16x8*)&PsWA[ln * 72 + ks * 32 + quad * 8];
                lA4 = __builtin_amdgcn_mfma_f32_16x16x32_bf16(apA, ones, lA4, 0, 0, 0);
            }
            apB = *(const bf16x8*)&PsWB[ln * 72 + ks * 32 + quad * 8];
            lB4 = __builtin_amdgcn_mfma_f32_16x16x32_bf16(apB, ones, lB4, 0, 0, 0);
#pragma unroll
            for (int d16 = 0; d16 < 4; d16++) {
                bf16x8 bv = *(const bf16x8*)&Vts[(d16 * 16 + ln) * 72 + ks * 32 + quad * 8];
                if (doA)
                    oA[d16] = __builtin_amdgcn_mfma_f32_16x16x32_bf16(apA, bv, oA[d16], 0, 0, 0);
                oB[d16] = __builtin_amdgcn_mfma_f32_16x16x32_bf16(apB, bv, oB[d16], 0, 0, 0);
            }
        }
    }

    // epilogue: normalize (l4 reg r = rowsum of row quad*4+r) and store
#pragma unroll
    for (int ph = 0; ph < 2; ph++) {
        f32x4* o = ph ? oB : oA;
        f32x4 l4 = ph ? lB4 : lA4;
        int qt = ph ? qb : qa;
        f32x4 inv = {1.f / l4[0], 1.f / l4[1], 1.f / l4[2], 1.f / l4[3]};
        const int tg = qt * 64 + wv * 16 + quad * 4;
#pragma unroll
        for (int d16 = 0; d16 < 4; d16++) {
#pragma unroll
            for (int r = 0; r < 4; r++) {
                float v = o[d16][r] * inv[r];
                Y[((size_t)b * T_SEQ + tg + r) * C_DIM + h * HD + d16 * 16 + ln] = f2bf(v);
            }
        }
    }
}

// ---------------------------------------------------------------------------
// Output projection: out[m,n] = sum_k Y[m,k] * Wp[n,k] + bp[n]  (fp32 out)
// ---------------------------------------------------------------------------
__global__ __launch_bounds__(256, 3)
void proj_gemm_kernel(const bf16_t* __restrict__ Yw, const bf16_t* __restrict__ Wpb,
                      const float* __restrict__ bp, float* __restrict__ out) {
    f32x4 acc[4][4];
    gemm_core_128(Yw, Wpb, acc);

    const int tid  = threadIdx.x;
    const int lane = tid & 63;
    const int wv2  = tid >> 6;
    const int wm   = wv2 >> 1, wn = wv2 & 1;
    const int quad = lane >> 4, ln = lane & 15;
    const int mbase = blockIdx.x * 128 + wm * 64;
    const int nbase = blockIdx.y * 128 + wn * 64;

#pragma unroll
    for (int j = 0; j < 4; j++) {
        int n = nbase + j * 16 + ln;
        float bj = bp[n];
#pragma unroll
        for (int i = 0; i < 4; i++) {
            int mr = mbase + i * 16 + quad * 4;
#pragma unroll
            for (int r = 0; r < 4; r++)
                out[(size_t)(mr + r) * C_DIM + n] = acc[i][j][r] + bj;
        }
    }
}

// ---------------------------------------------------------------------------
extern "C" void kernel_launch(void* const* d_in, const int* in_sizes, int n_in,
                              void* d_out, int out_size, void* d_ws, size_t ws_size,
                              hipStream_t stream) {
    const float* x  = (const float*)d_in[0];
    const float* Wq = (const float*)d_in[1];
    const float* bq = (const float*)d_in[2];
    const float* Wk = (const float*)d_in[3];
    const float* bk = (const float*)d_in[4];
    const float* Wv = (const float*)d_in[5];
    const float* bv = (const float*)d_in[6];
    const float* Wp = (const float*)d_in[7];
    const float* bp = (const float*)d_in[8];
    float* out = (float*)d_out;

    char* ws = (char*)d_ws;
    const size_t MB = (size_t)1 << 20;
    ushort_t* Qw = (ushort_t*)(ws);            // 16 MB  [B,H,T,D] bf16 (pre-scaled)
    ushort_t* Kw = (ushort_t*)(ws + 16 * MB);  // 16 MB  [B,H,T,D] bf16
    ushort_t* Vt = (ushort_t*)(ws + 32 * MB);  // 16 MB  [B,H,D,T] bf16
    ushort_t* Yw = (ushort_t*)(ws + 48 * MB);  // 16 MB  [B,T,C]   bf16
    ushort_t* Wpb = (ushort_t*)(ws);           // 2 MB, reuses Qw region AFTER flash

    // d_out doubles as bf16 scratch for converted inputs; proj overwrites it.
    ushort_t* xb  = (ushort_t*)out;                     // 16 MB
    ushort_t* Wqb = (ushort_t*)((char*)out + 16 * MB);  // 2 MB
    ushort_t* Wkb = (ushort_t*)((char*)out + 18 * MB);  // 2 MB
    ushort_t* Wvb = (ushort_t*)((char*)out + 20 * MB);  // 2 MB

    cvt_all_kernel<<<11264, 256, 0, stream>>>(x, Wq, Wk, Wv, xb, Wqb, Wkb, Wvb);

    dim3 g1(64, 8, 3);
    qkv_gemm_kernel<<<g1, 256, 0, stream>>>((const bf16_t*)xb,
                                            (const bf16_t*)Wqb, bq,
                                            (const bf16_t*)Wkb, bk,
                                            (const bf16_t*)Wvb, bv,
                                            Qw, Kw, Vt);

    dim3 g2(16, 64);   // (paired q-tiles, B*H)
    flash_kernel<<<g2, 256, 0, stream>>>(Qw, Kw, Vt, Yw);

    cvt_wp_kernel<<<1024, 256, 0, stream>>>(Wp, Wpb);

    dim3 g3(64, 8, 1);
    proj_gemm_kernel<<<g3, 256, 0, stream>>>((const bf16_t*)Yw, (const bf16_t*)Wpb, bp, out);
}

// Round 3
// 239.889 us; speedup vs baseline: 1.1429x; 1.0354x over previous
//
#include <hip/hip_runtime.h>

typedef __bf16 bf16_t;
typedef __bf16 bf16x8 __attribute__((ext_vector_type(8)));
typedef __bf16 bf16x4 __attribute__((ext_vector_type(4)));
typedef float f32x4 __attribute__((ext_vector_type(4)));
typedef unsigned short ushort_t;

#define T_SEQ 2048
#define C_DIM 1024
#define NH    16
#define HD    64

__device__ __forceinline__ ushort_t f2bf(float f) {
    unsigned u = __builtin_bit_cast(unsigned, f);
    u += 0x7FFFu + ((u >> 16) & 1u);   // RNE
    return (ushort_t)(u >> 16);
}

// async 16B global -> LDS (direct, no VGPR round-trip)
__device__ __forceinline__ void async_cp16(const void* g, void* l) {
    __builtin_amdgcn_global_load_lds(
        (const __attribute__((address_space(1))) void*)g,
        (__attribute__((address_space(3))) void*)l, 16, 0, 0);
}

// ---------------------------------------------------------------------------
// Unified fp32 -> bf16 conversion for x, Wq, Wk, Wv (single launch).
// ---------------------------------------------------------------------------
#define X4  2097152
#define W4  262144
__global__ __launch_bounds__(256)
void cvt_all_kernel(const float* __restrict__ x,  const float* __restrict__ Wq,
                    const float* __restrict__ Wk, const float* __restrict__ Wv,
                    ushort_t* __restrict__ xb,  ushort_t* __restrict__ Wqb,
                    ushort_t* __restrict__ Wkb, ushort_t* __restrict__ Wvb) {
    int i = blockIdx.x * 256 + threadIdx.x;
    const float* src; ushort_t* dst; int off;
    if (i < X4)                { src = x;  dst = xb;  off = i; }
    else if (i < X4 + W4)      { src = Wq; dst = Wqb; off = i - X4; }
    else if (i < X4 + 2 * W4)  { src = Wk; dst = Wkb; off = i - X4 - W4; }
    else                       { src = Wv; dst = Wvb; off = i - X4 - 2 * W4; }
    float4 f = ((const float4*)src)[off];
    ushort4 u;
    u.x = f2bf(f.x); u.y = f2bf(f.y); u.z = f2bf(f.z); u.w = f2bf(f.w);
    ((ushort4*)dst)[off] = u;
}

// fp32 -> bf16 for Wp (runs after flash; Wpb lives in the dead Qw region)
__global__ __launch_bounds__(256)
void cvt_wp_kernel(const float* __restrict__ Wp, ushort_t* __restrict__ Wpb) {
    int i = blockIdx.x * 256 + threadIdx.x;   // 262144 float4
    float4 f = ((const float4*)Wp)[i];
    ushort4 u;
    u.x = f2bf(f.x); u.y = f2bf(f.y); u.z = f2bf(f.z); u.w = f2bf(f.w);
    ((ushort4*)Wpb)[i] = u;
}

// ---------------------------------------------------------------------------
// GEMM core: 128x128 tile, BK=64, 256 threads (4 waves, 2x2), NT layout,
// all-bf16.  Staging via global_load_lds (16B/lane, linear LDS dest).
// XOR swizzle via pre-swizzled GLOBAL source; fragment reads apply the same
// involution -> conflict-free ds_read_b128.
// ---------------------------------------------------------------------------
__device__ __forceinline__ void gemm_core_128(const bf16_t* __restrict__ A,
                                              const bf16_t* __restrict__ B,
                                              f32x4 (&acc)[4][4]) {
    __shared__ alignas(16) ushort_t As[128 * 64];
    __shared__ alignas(16) ushort_t Ws[128 * 64];
    const int tid  = threadIdx.x;
    const int lane = tid & 63;
    const int wv   = tid >> 6;
    const int wm   = wv >> 1, wn = wv & 1;
    const int quad = lane >> 4, ln = lane & 15;
    const int m0 = blockIdx.x * 128, n0 = blockIdx.y * 128;

    f32x4 z4 = {0.f, 0.f, 0.f, 0.f};
#pragma unroll
    for (int i = 0; i < 4; i++)
#pragma unroll
        for (int j = 0; j < 4; j++) acc[i][j] = z4;

    const int lr = lane >> 3;            // row within 8-row chunk
    const int lc = (lane & 7) ^ lr;      // swizzled source 16B-block
    const bf16_t* Ab = A + (size_t)(m0 + wv * 32 + lr) * 1024 + lc * 8;
    const bf16_t* Bb = B + (size_t)(n0 + wv * 32 + lr) * 1024 + lc * 8;

    for (int kt = 0; kt < 1024; kt += 64) {
#pragma unroll
        for (int p = 0; p < 4; ++p) {
            async_cp16(Ab + (size_t)p * 8192 + kt, &As[(wv * 4 + p) * 512]);
            async_cp16(Bb + (size_t)p * 8192 + kt, &Ws[(wv * 4 + p) * 512]);
        }
        __syncthreads();
#pragma unroll
        for (int ks = 0; ks < 2; ++ks) {
            bf16x8 af[4], bfr[4];
#pragma unroll
            for (int i = 0; i < 4; i++)
                af[i] = *(const bf16x8*)&As[(wm * 64 + i * 16 + ln) * 64 +
                                            (((ks * 4 + quad) ^ (ln & 7)) * 8)];
#pragma unroll
            for (int j = 0; j < 4; j++)
                bfr[j] = *(const bf16x8*)&Ws[(wn * 64 + j * 16 + ln) * 64 +
                                             (((ks * 4 + quad) ^ (ln & 7)) * 8)];
#pragma unroll
            for (int i = 0; i < 4; i++)
#pragma unroll
                for (int j = 0; j < 4; j++)
                    acc[i][j] = __builtin_amdgcn_mfma_f32_16x16x32_bf16(af[i], bfr[j],
                                                                        acc[i][j], 0, 0, 0);
        }
        __syncthreads();
    }
}

// ---------------------------------------------------------------------------
// QKV projection (all-bf16 inputs).  z=0: Q (pre-scaled by cscale) -> [B,H,T,D];
// z=1: K -> [B,H,T,D]; z=2: V -> [B,H,D,T].  Biases fp32.
// ---------------------------------------------------------------------------
__global__ __launch_bounds__(256, 3)
void qkv_gemm_kernel(const bf16_t* __restrict__ xb,
                     const bf16_t* __restrict__ Wqb, const float* __restrict__ bq,
                     const bf16_t* __restrict__ Wkb, const float* __restrict__ bk,
                     const bf16_t* __restrict__ Wvb, const float* __restrict__ bv,
                     ushort_t* __restrict__ Qo, ushort_t* __restrict__ Ko,
                     ushort_t* __restrict__ Vo) {
    const int z = blockIdx.z;
    const bf16_t* W   = (z == 0) ? Wqb : (z == 1) ? Wkb : Wvb;
    const float* bias = (z == 0) ? bq : (z == 1) ? bk : bv;
    ushort_t* outp    = (z == 0) ? Qo : (z == 1) ? Ko : Vo;
    const float fs    = (z == 0) ? 0.18033688011112042f : 1.0f;  // (1/8)*log2(e)

    f32x4 acc[4][4];
    gemm_core_128(xb, W, acc);

    const int tid  = threadIdx.x;
    const int lane = tid & 63;
    const int wv2  = tid >> 6;
    const int wm   = wv2 >> 1, wn = wv2 & 1;
    const int quad = lane >> 4, ln = lane & 15;
    const int mbase = blockIdx.x * 128 + wm * 64;
    const int nbase = blockIdx.y * 128 + wn * 64;

#pragma unroll
    for (int j = 0; j < 4; j++) {
        int n = nbase + j * 16 + ln;
        float bj = bias[n];
        int h = n >> 6, d = n & 63;
#pragma unroll
        for (int i = 0; i < 4; i++) {
            int mr = mbase + i * 16 + quad * 4;
            int b = mr >> 11;
            int t = mr & 2047;
            if (z < 2) {
                ushort_t* op = outp + ((size_t)(b * NH + h) * T_SEQ + t) * HD + d;
#pragma unroll
                for (int r = 0; r < 4; r++)
                    op[(size_t)r * HD] = f2bf((acc[i][j][r] + bj) * fs);
            } else {
                ushort4 us;
                us.x = f2bf(acc[i][j][0] + bj);
                us.y = f2bf(acc[i][j][1] + bj);
                us.z = f2bf(acc[i][j][2] + bj);
                us.w = f2bf(acc[i][j][3] + bj);
                *(ushort4*)(outp + ((size_t)(b * NH + h) * HD + d) * T_SEQ + t) = us;
            }
        }
    }
}

// ---------------------------------------------------------------------------
// Flash attention (causal), paired q-tiles (p, 31-p), P HELD IN REGISTERS.
//
// Swapped QK: zz = mfma(K,Q) -> lane (quad,ln) holds P[q=ln][s=n16*16+quad*4+r].
// PV uses a PERMUTED k-order chosen to match where those values already sit:
//   ap[ks] slots = {zz[2ks][r0..3], zz[2ks+1][r0..3]}
// i.e. lane quad's k-slots quad*8+j hold s = 32ks+4quad+r  /  32ks+16+4quad+r.
// V is staged into LDS in the SAME s-permutation (kpos below), so
// mfma(ap, bv) sums over matching s.  Rowsum-MFMA vs all-ones is
// permutation-invariant.  No Ps LDS, no round-trip, no extra lgkm waits.
// ---------------------------------------------------------------------------
__device__ __forceinline__ int vkpos(int s) {   // k-slot position of s in [0,64)
    return 32 * (s >> 5) + 8 * ((s >> 2) & 3) + 4 * ((s >> 4) & 1) + (s & 3);
}

__global__ __launch_bounds__(256, 4)
void flash_kernel(const ushort_t* __restrict__ Qw, const ushort_t* __restrict__ Kw,
                  const ushort_t* __restrict__ Vt, ushort_t* __restrict__ Y) {
    __shared__ alignas(16) ushort_t Ks[64 * 72];
    __shared__ alignas(16) ushort_t Vts[64 * 72];

    const int tid  = threadIdx.x;
    const int lane = tid & 63;
    const int wv   = tid >> 6;
    const int quad = lane >> 4, ln = lane & 15;
    // bijective XCD-aware remap of (p, bh)
    const int L  = blockIdx.y * 16 + blockIdx.x;      // hw dispatch-linear id
    const int m  = L >> 3;
    const int bh = ((m >> 4) << 3) | (L & 7);         // same bh -> same L%8 (XCD)
    const int p  = m & 15;                            // 0..15
    const int qa = p, qb = 31 - p;
    const int b = bh >> 4, h = bh & 15;

    bf16x8 ones;
#pragma unroll
    for (int i = 0; i < 8; i++) ones[i] = (bf16_t)1.0f;

    const ushort_t* qpa = Qw + ((size_t)bh * T_SEQ + qa * 64 + wv * 16 + ln) * HD;
    const ushort_t* qpb = Qw + ((size_t)bh * T_SEQ + qb * 64 + wv * 16 + ln) * HD;
    bf16x8 aqA0 = *(const bf16x8*)(qpa + quad * 8);
    bf16x8 aqA1 = *(const bf16x8*)(qpa + 32 + quad * 8);
    bf16x8 aqB0 = *(const bf16x8*)(qpb + quad * 8);
    bf16x8 aqB1 = *(const bf16x8*)(qpb + 32 + quad * 8);

    f32x4 oA[4], oB[4];
    f32x4 z4 = {0.f, 0.f, 0.f, 0.f};
#pragma unroll
    for (int i = 0; i < 4; i++) { oA[i] = z4; oB[i] = z4; }
    f32x4 lA4 = z4, lB4 = z4;

    const int row0 = tid >> 3, c80 = (tid & 7) * 8;
    const int row1 = (256 + tid) >> 3;
    const int kp0 = vkpos(c80);          // V k-slot for s = c80..c80+3
    const int kp1 = vkpos(c80 + 4);      // V k-slot for s = c80+4..c80+7

    uint4 pk0, pk1, pv0, pv1;
    pk0 = *(const uint4*)(Kw + ((size_t)bh * T_SEQ + row0) * HD + c80);
    pv0 = *(const uint4*)(Vt + ((size_t)bh * HD + row0) * T_SEQ + c80);
    pk1 = *(const uint4*)(Kw + ((size_t)bh * T_SEQ + row1) * HD + c80);
    pv1 = *(const uint4*)(Vt + ((size_t)bh * HD + row1) * T_SEQ + c80);

    const int qrow = wv * 16 + ln;       // this lane's q position within tile

    for (int st = 0; st <= qb; ++st) {
        __syncthreads();
        *(uint4*)&Ks[row0 * 72 + c80] = pk0;
        *(uint4*)&Ks[row1 * 72 + c80] = pk1;
        {   // V: permuted placement, two b64 per former b128
            uint2 a0 = {pv0.x, pv0.y}, a1 = {pv0.z, pv0.w};
            uint2 b0 = {pv1.x, pv1.y}, b1 = {pv1.z, pv1.w};
            *(uint2*)&Vts[row0 * 72 + kp0] = a0;
            *(uint2*)&Vts[row0 * 72 + kp1] = a1;
            *(uint2*)&Vts[row1 * 72 + kp0] = b0;
            *(uint2*)&Vts[row1 * 72 + kp1] = b1;
        }
        if (st < qb) {
            int s1 = (st + 1) * 64;
            pk0 = *(const uint4*)(Kw + ((size_t)bh * T_SEQ + s1 + row0) * HD + c80);
            pv0 = *(const uint4*)(Vt + ((size_t)bh * HD + row0) * T_SEQ + s1 + c80);
            pk1 = *(const uint4*)(Kw + ((size_t)bh * T_SEQ + s1 + row1) * HD + c80);
            pv1 = *(const uint4*)(Vt + ((size_t)bh * HD + row1) * T_SEQ + s1 + c80);
        }
        __syncthreads();

        const bool doA = (st <= qa);
        const bool dgA = (st == qa), dgB = (st == qb);

        // QK^T + softmax-exp, P packed straight into PV A-fragments (regs)
        bf16x8 apA[2], apB[2];
#pragma unroll
        for (int n16 = 0; n16 < 4; n16++) {
            bf16x8 bk0 = *(const bf16x8*)&Ks[(n16 * 16 + ln) * 72 + quad * 8];
            bf16x8 bk1 = *(const bf16x8*)&Ks[(n16 * 16 + ln) * 72 + 32 + quad * 8];
            const int ks = n16 >> 1, hf = (n16 & 1) * 4;
            f32x4 zB = {0.f, 0.f, 0.f, 0.f};
            zB = __builtin_amdgcn_mfma_f32_16x16x32_bf16(bk0, aqB0, zB, 0, 0, 0);
            zB = __builtin_amdgcn_mfma_f32_16x16x32_bf16(bk1, aqB1, zB, 0, 0, 0);
            if (doA) {
                f32x4 zA = {0.f, 0.f, 0.f, 0.f};
                zA = __builtin_amdgcn_mfma_f32_16x16x32_bf16(bk0, aqA0, zA, 0, 0, 0);
                zA = __builtin_amdgcn_mfma_f32_16x16x32_bf16(bk1, aqA1, zA, 0, 0, 0);
#pragma unroll
                for (int r = 0; r < 4; r++) {
                    float v = zA[r];
                    v = (dgA && (n16 * 16 + quad * 4 + r > qrow)) ? -1e30f : v;
                    apA[ks][hf + r] = (bf16_t)__builtin_amdgcn_exp2f(v);
                }
            }
#pragma unroll
            for (int r = 0; r < 4; r++) {
                float v = zB[r];
                v = (dgB && (n16 * 16 + quad * 4 + r > qrow)) ? -1e30f : v;
                apB[ks][hf + r] = (bf16_t)__builtin_amdgcn_exp2f(v);
            }
        }

        // merged PV: each V fragment read once, feeds both phases' MFMAs
#pragma unroll
        for (int ks = 0; ks < 2; ks++) {
            if (doA)
                lA4 = __builtin_amdgcn_mfma_f32_16x16x32_bf16(apA[ks], ones, lA4, 0, 0, 0);
            lB4 = __builtin_amdgcn_mfma_f32_16x16x32_bf16(apB[ks], ones, lB4, 0, 0, 0);
#pragma unroll
            for (int d16 = 0; d16 < 4; d16++) {
                bf16x8 bv = *(const bf16x8*)&Vts[(d16 * 16 + ln) * 72 + ks * 32 + quad * 8];
                if (doA)
                    oA[d16] = __builtin_amdgcn_mfma_f32_16x16x32_bf16(apA[ks], bv, oA[d16], 0, 0, 0);
                oB[d16] = __builtin_amdgcn_mfma_f32_16x16x32_bf16(apB[ks], bv, oB[d16], 0, 0, 0);
            }
        }
    }

    // epilogue: normalize (l4 reg r = rowsum of row quad*4+r) and store
#pragma unroll
    for (int ph = 0; ph < 2; ph++) {
        f32x4* o = ph ? oB : oA;
        f32x4 l4 = ph ? lB4 : lA4;
        int qt = ph ? qb : qa;
        f32x4 inv = {1.f / l4[0], 1.f / l4[1], 1.f / l4[2], 1.f / l4[3]};
        const int tg = qt * 64 + wv * 16 + quad * 4;
#pragma unroll
        for (int d16 = 0; d16 < 4; d16++) {
#pragma unroll
            for (int r = 0; r < 4; r++) {
                float v = o[d16][r] * inv[r];
                Y[((size_t)b * T_SEQ + tg + r) * C_DIM + h * HD + d16 * 16 + ln] = f2bf(v);
            }
        }
    }
}

// ---------------------------------------------------------------------------
// Output projection: out[m,n] = sum_k Y[m,k] * Wp[n,k] + bp[n]  (fp32 out)
// ---------------------------------------------------------------------------
__global__ __launch_bounds__(256, 3)
void proj_gemm_kernel(const bf16_t* __restrict__ Yw, const bf16_t* __restrict__ Wpb,
                      const float* __restrict__ bp, float* __restrict__ out) {
    f32x4 acc[4][4];
    gemm_core_128(Yw, Wpb, acc);

    const int tid  = threadIdx.x;
    const int lane = tid & 63;
    const int wv2  = tid >> 6;
    const int wm   = wv2 >> 1, wn = wv2 & 1;
    const int quad = lane >> 4, ln = lane & 15;
    const int mbase = blockIdx.x * 128 + wm * 64;
    const int nbase = blockIdx.y * 128 + wn * 64;

#pragma unroll
    for (int j = 0; j < 4; j++) {
        int n = nbase + j * 16 + ln;
        float bj = bp[n];
#pragma unroll
        for (int i = 0; i < 4; i++) {
            int mr = mbase + i * 16 + quad * 4;
#pragma unroll
            for (int r = 0; r < 4; r++)
                out[(size_t)(mr + r) * C_DIM + n] = acc[i][j][r] + bj;
        }
    }
}

// ---------------------------------------------------------------------------
extern "C" void kernel_launch(void* const* d_in, const int* in_sizes, int n_in,
                              void* d_out, int out_size, void* d_ws, size_t ws_size,
                              hipStream_t stream) {
    const float* x  = (const float*)d_in[0];
    const float* Wq = (const float*)d_in[1];
    const float* bq = (const float*)d_in[2];
    const float* Wk = (const float*)d_in[3];
    const float* bk = (const float*)d_in[4];
    const float* Wv = (const float*)d_in[5];
    const float* bv = (const float*)d_in[6];
    const float* Wp = (const float*)d_in[7];
    const float* bp = (const float*)d_in[8];
    float* out = (float*)d_out;

    char* ws = (char*)d_ws;
    const size_t MB = (size_t)1 << 20;
    ushort_t* Qw = (ushort_t*)(ws);            // 16 MB  [B,H,T,D] bf16 (pre-scaled)
    ushort_t* Kw = (ushort_t*)(ws + 16 * MB);  // 16 MB  [B,H,T,D] bf16
    ushort_t* Vt = (ushort_t*)(ws + 32 * MB);  // 16 MB  [B,H,D,T] bf16
    ushort_t* Yw = (ushort_t*)(ws + 48 * MB);  // 16 MB  [B,T,C]   bf16
    ushort_t* Wpb = (ushort_t*)(ws);           // 2 MB, reuses Qw region AFTER flash

    // d_out doubles as bf16 scratch for converted inputs; proj overwrites it.
    ushort_t* xb  = (ushort_t*)out;                     // 16 MB
    ushort_t* Wqb = (ushort_t*)((char*)out + 16 * MB);  // 2 MB
    ushort_t* Wkb = (ushort_t*)((char*)out + 18 * MB);  // 2 MB
    ushort_t* Wvb = (ushort_t*)((char*)out + 20 * MB);  // 2 MB

    cvt_all_kernel<<<11264, 256, 0, stream>>>(x, Wq, Wk, Wv, xb, Wqb, Wkb, Wvb);

    dim3 g1(64, 8, 3);
    qkv_gemm_kernel<<<g1, 256, 0, stream>>>((const bf16_t*)xb,
                                            (const bf16_t*)Wqb, bq,
                                            (const bf16_t*)Wkb, bk,
                                            (const bf16_t*)Wvb, bv,
                                            Qw, Kw, Vt);

    dim3 g2(16, 64);   // (paired q-tiles, B*H)
    flash_kernel<<<g2, 256, 0, stream>>>(Qw, Kw, Vt, Yw);

    cvt_wp_kernel<<<1024, 256, 0, stream>>>(Wp, Wpb);

    dim3 g3(64, 8, 1);
    proj_gemm_kernel<<<g3, 256, 0, stream>>>((const bf16_t*)Yw, (const bf16_t*)Wpb, bp, out);
}